// Round 3
// baseline (3905.288 us; speedup 1.0000x reference)
//
#include <hip/hip_runtime.h>
#include <math.h>

#define N_NODES 50000
#define N_EDGES 1600000
#define HID 128
#define NF 128
#define NG 50
#define NL 6
#define NSEG 64
#define TAB 2048
#define CUTOFF 20.0f
#define LOG2F_ 0.6931471805599453f

typedef unsigned short u16;

__device__ __forceinline__ float ssp(float x){
  float sp = fmaxf(x, 0.f) + log1pf(expf(-fabsf(x)));
  return sp - LOG2F_;
}
__device__ __forceinline__ float b2f(u16 u){
  unsigned v = ((unsigned)u) << 16; float f; __builtin_memcpy(&f, &v, 4); return f;
}
__device__ __forceinline__ u16 f2b(float f){
  unsigned u; __builtin_memcpy(&u, &f, 4);
  u += 0x7FFFu + ((u >> 16) & 1u);
  return (u16)(u >> 16);
}

// ---------------- edge distance + degree histogram (fused) ----------------
__global__ __launch_bounds__(256) void k_dist(const int* __restrict__ ei,
                                              const float* __restrict__ pos,
                                              float* __restrict__ dist,
                                              int* __restrict__ deg){
  for (int e = blockIdx.x*blockDim.x + threadIdx.x; e < N_EDGES; e += gridDim.x*blockDim.x){
    int s = ei[e], t = ei[N_EDGES + e];
    float dx = pos[3*s]   - pos[3*t];
    float dy = pos[3*s+1] - pos[3*t+1];
    float dz = pos[3*s+2] - pos[3*t+2];
    dist[e] = sqrtf(dx*dx + dy*dy + dz*dz);
    atomicAdd(&deg[t], 1);
  }
}

__global__ __launch_bounds__(1024) void k_scan(const int* __restrict__ deg, int* __restrict__ row_start){
  __shared__ int sums[1024];
  const int t = threadIdx.x;
  const int CH = (N_NODES + 1023) / 1024; // 49
  const int base = t * CH;
  int s = 0;
  for (int i = 0; i < CH; i++){ int idx = base + i; if (idx < N_NODES) s += deg[idx]; }
  sums[t] = s; __syncthreads();
  for (int off = 1; off < 1024; off <<= 1){
    int v = (t >= off) ? sums[t - off] : 0;
    __syncthreads();
    sums[t] += v;
    __syncthreads();
  }
  int run = (t == 0) ? 0 : sums[t - 1];
  for (int i = 0; i < CH; i++){
    int idx = base + i;
    if (idx < N_NODES){ row_start[idx] = run; run += deg[idx]; }
  }
  if (t == 1023) row_start[N_NODES] = run;
}

__global__ __launch_bounds__(256) void k_scatter(const int* __restrict__ ei,
                                                 const float* __restrict__ dist,
                                                 const int* __restrict__ row_start,
                                                 int* __restrict__ cursor,
                                                 int* __restrict__ csr_src,
                                                 float* __restrict__ csr_d){
  for (int e = blockIdx.x*blockDim.x + threadIdx.x; e < N_EDGES; e += gridDim.x*blockDim.x){
    int dn = ei[N_EDGES + e];
    int slot = atomicAdd(&cursor[dn], 1);
    int p = row_start[dn] + slot;
    csr_src[p] = ei[e];
    csr_d[p]   = dist[e];
  }
}

// ---------------- filter table: W_l(d)*C(d), bf16, rows j and j+1 interleaved ----------------
// tabi[((l*TAB + j)*NF + f)*2 + 0] = W_j[f];  ...*2 + 1] = W_{j+1}[f]
__global__ __launch_bounds__(128) void k_table(const float* __restrict__ w1, const float* __restrict__ b1,
                                               const float* __restrict__ w2, const float* __restrict__ b2,
                                               u16* __restrict__ tabi){
  int l = blockIdx.x / TAB, j = blockIdx.x % TAB;
  int tid = threadIdx.x;
  float d = j * (CUTOFF / (TAB - 1));
  __shared__ float ea[NG];
  __shared__ float sbuf[NF];
  if (tid < NG){
    const float gstep = CUTOFF / (NG - 1);
    const float coeff = -0.5f / (gstep * gstep);
    float u = d - tid * gstep;
    ea[tid] = expf(coeff * u * u);
  }
  __syncthreads();
  float z = b1[l*NF + tid];
  for (int k = 0; k < NG; k++) z += ea[k] * w1[(l*NG + k)*NF + tid];
  sbuf[tid] = ssp(z);
  __syncthreads();
  float W = b2[l*NF + tid];
  for (int k = 0; k < NF; k++) W += sbuf[k] * w2[(l*NF + k)*NF + tid];
  float C = 0.5f * (cosf(d * (float)M_PI / CUTOFF) + 1.f);
  u16 wb = f2b(W * C);
  tabi[(((size_t)l*TAB + j)*NF + tid)*2] = wb;
  if (j > 0)        tabi[(((size_t)l*TAB + j - 1)*NF + tid)*2 + 1] = wb;
  if (j == TAB - 1) tabi[(((size_t)l*TAB + j)*NF + tid)*2 + 1] = wb;
}

// ---------------- hx0 = h @ conv_lin1_w[0] (shuffle matvec, bf16 out) ----------------
__global__ __launch_bounds__(128) void k_lin1b(const float* __restrict__ h,
                                               const float* __restrict__ w,
                                               u16* __restrict__ hxb){
  int tid = threadIdx.x, lane = tid & 63;
  int n0 = blockIdx.x * 8;
  float h0[8], h1[8];
  #pragma unroll
  for (int r = 0; r < 8; r++){
    h0[r] = h[(size_t)(n0 + r)*HID + lane];
    h1[r] = h[(size_t)(n0 + r)*HID + 64 + lane];
  }
  float acc[8];
  #pragma unroll
  for (int r = 0; r < 8; r++) acc[r] = 0.f;
  for (int k = 0; k < 64; k++){
    float wv = w[k*NF + tid];
    #pragma unroll
    for (int r = 0; r < 8; r++) acc[r] += __shfl(h0[r], k) * wv;
  }
  for (int k = 0; k < 64; k++){
    float wv = w[(64 + k)*NF + tid];
    #pragma unroll
    for (int r = 0; r < 8; r++) acc[r] += __shfl(h1[r], k) * wv;
  }
  #pragma unroll
  for (int r = 0; r < 8; r++) hxb[(size_t)(n0 + r)*NF + tid] = f2b(acc[r]);
}

// ---------------- edge aggregation: one wave per node, 2 features/lane, bf16 gathers ----------------
__global__ __launch_bounds__(256) void k_edgeagg(const int* __restrict__ row_start,
                                                 const int* __restrict__ csr_src,
                                                 const float* __restrict__ csr_d,
                                                 const u16* __restrict__ tabi_l,
                                                 const u16* __restrict__ hxb,
                                                 float* __restrict__ agg){
  int wave = threadIdx.x >> 6, lane = threadIdx.x & 63;
  int i = blockIdx.x * 4 + wave;
  int rs = row_start[i], re = row_start[i + 1];
  const float INV_STEP = (TAB - 1) / CUTOFF;
  float acc0 = 0.f, acc1 = 0.f;
  for (int p = rs; p < re; ++p){
    int s = csr_src[p];
    float dv = csr_d[p];
    float t = dv * INV_STEP;
    t = fminf(fmaxf(t, 0.f), (float)(TAB - 1) - 0.001f);
    int i0 = (int)t;
    float fr = t - (float)i0;
    ushort2 hv = *(const ushort2*)&hxb[(size_t)s * NF + 2*lane];
    ushort4 wv = *(const ushort4*)&tabi_l[((size_t)i0 * NF + 2*lane)*2];
    float w00 = b2f(wv.x), w01 = b2f(wv.y);   // feature f0: rows j, j+1
    float w10 = b2f(wv.z), w11 = b2f(wv.w);   // feature f1: rows j, j+1
    float W0 = w00 + fr * (w01 - w00);
    float W1 = w10 + fr * (w11 - w10);
    acc0 += b2f(hv.x) * W0;
    acc1 += b2f(hv.y) * W1;
  }
  float2 o; o.x = acc0; o.y = acc1;
  *(float2*)&agg[(size_t)i * NF + 2*lane] = o;
}

// ---------------- fused node update + next-layer lin1 ----------------
// h += ssp(agg@w2b + b2b) @ linw + linb ;  if (w1n) hxb = bf16(h_new @ w1n)
__global__ __launch_bounds__(128) void k_nodefuse(const float* __restrict__ agg,
                                                  const float* __restrict__ w2b, const float* __restrict__ b2b,
                                                  const float* __restrict__ linw, const float* __restrict__ linb,
                                                  float* __restrict__ h,
                                                  const float* __restrict__ w1n,
                                                  u16* __restrict__ hxb){
  int tid = threadIdx.x, lane = tid & 63;
  int n0 = blockIdx.x * 8;
  __shared__ float xs[8][HID];

  float a0[8], a1[8];
  #pragma unroll
  for (int r = 0; r < 8; r++){
    a0[r] = agg[(size_t)(n0 + r)*NF + lane];
    a1[r] = agg[(size_t)(n0 + r)*NF + 64 + lane];
  }
  float acc[8];
  #pragma unroll
  for (int r = 0; r < 8; r++) acc[r] = b2b[tid];
  for (int k = 0; k < 64; k++){
    float wv = w2b[k*HID + tid];
    #pragma unroll
    for (int r = 0; r < 8; r++) acc[r] += __shfl(a0[r], k) * wv;
  }
  for (int k = 0; k < 64; k++){
    float wv = w2b[(64 + k)*HID + tid];
    #pragma unroll
    for (int r = 0; r < 8; r++) acc[r] += __shfl(a1[r], k) * wv;
  }
  // s = ssp(acc); exchange halves via LDS
  #pragma unroll
  for (int r = 0; r < 8; r++) xs[r][tid] = ssp(acc[r]);
  __syncthreads();
  float s0[8], s1[8];
  #pragma unroll
  for (int r = 0; r < 8; r++){ s0[r] = xs[r][lane]; s1[r] = xs[r][64 + lane]; }
  #pragma unroll
  for (int r = 0; r < 8; r++) acc[r] = linb[tid];
  for (int k = 0; k < 64; k++){
    float wv = linw[k*HID + tid];
    #pragma unroll
    for (int r = 0; r < 8; r++) acc[r] += __shfl(s0[r], k) * wv;
  }
  for (int k = 0; k < 64; k++){
    float wv = linw[(64 + k)*HID + tid];
    #pragma unroll
    for (int r = 0; r < 8; r++) acc[r] += __shfl(s1[r], k) * wv;
  }
  // residual update
  float hn[8];
  #pragma unroll
  for (int r = 0; r < 8; r++){
    hn[r] = h[(size_t)(n0 + r)*HID + tid] + acc[r];
    h[(size_t)(n0 + r)*HID + tid] = hn[r];
  }
  if (w1n){
    __syncthreads();
    #pragma unroll
    for (int r = 0; r < 8; r++) xs[r][tid] = hn[r];
    __syncthreads();
    float h0[8], h1[8];
    #pragma unroll
    for (int r = 0; r < 8; r++){ h0[r] = xs[r][lane]; h1[r] = xs[r][64 + lane]; }
    #pragma unroll
    for (int r = 0; r < 8; r++) acc[r] = 0.f;
    for (int k = 0; k < 64; k++){
      float wv = w1n[k*NF + tid];
      #pragma unroll
      for (int r = 0; r < 8; r++) acc[r] += __shfl(h0[r], k) * wv;
    }
    for (int k = 0; k < 64; k++){
      float wv = w1n[(64 + k)*NF + tid];
      #pragma unroll
      for (int r = 0; r < 8; r++) acc[r] += __shfl(h1[r], k) * wv;
    }
    #pragma unroll
    for (int r = 0; r < 8; r++) hxb[(size_t)(n0 + r)*NF + tid] = f2b(acc[r]);
  }
}

// ---------------- readout: contiguous chunk per wave, run-length segment sum ----------------
__global__ __launch_bounds__(256) void k_out(const float* __restrict__ h,
                                             const float* __restrict__ w1, const float* __restrict__ b1,
                                             const float* __restrict__ w2, const float* __restrict__ b2,
                                             const int* __restrict__ batch, float* __restrict__ out){
  __shared__ float w1s[HID * 64];
  int tid = threadIdx.x;
  for (int k = tid; k < HID * 64; k += 256) w1s[k] = w1[k];
  __syncthreads();
  int wave = tid >> 6, lane = tid & 63;
  int gwave = blockIdx.x * 4 + wave;
  const int NWAVES = 256 * 4;
  const int CHUNK = (N_NODES + NWAVES - 1) / NWAVES; // 49
  int n0 = gwave * CHUNK;
  int n1 = n0 + CHUNK; if (n1 > N_NODES) n1 = N_NODES;
  float b1v = b1[lane];
  float w2v = w2[lane];
  float b2v = b2[0];
  float run = 0.f; int curseg = -1;
  for (int n = n0; n < n1; ++n){
    float h0 = h[(size_t)n * HID + lane];
    float h1 = h[(size_t)n * HID + 64 + lane];
    float acc = b1v;
    #pragma unroll
    for (int k = 0; k < 64; k++){
      float hb = __shfl(h0, k);
      acc += hb * w1s[k * 64 + lane];
    }
    #pragma unroll
    for (int k = 0; k < 64; k++){
      float hb = __shfl(h1, k);
      acc += hb * w1s[(64 + k) * 64 + lane];
    }
    float p = ssp(acc) * w2v;
    #pragma unroll
    for (int off = 32; off >= 1; off >>= 1) p += __shfl_xor(p, off);
    if (lane == 0){
      int seg = batch[n];
      if (seg != curseg){
        if (curseg >= 0) atomicAdd(&out[curseg], run);
        curseg = seg; run = 0.f;
      }
      run += p + b2v;
    }
  }
  if (lane == 0 && curseg >= 0) atomicAdd(&out[curseg], run);
}

extern "C" void kernel_launch(void* const* d_in, const int* in_sizes, int n_in,
                              void* d_out, int out_size, void* d_ws, size_t ws_size,
                              hipStream_t stream) {
  const float* h     = (const float*)d_in[0];
  const float* pos   = (const float*)d_in[1];
  const int*   ei    = (const int*)d_in[2];
  const int*   batch = (const int*)d_in[3];
  const float* mlp_w1 = (const float*)d_in[4];
  const float* mlp_b1 = (const float*)d_in[5];
  const float* mlp_w2 = (const float*)d_in[6];
  const float* mlp_b2 = (const float*)d_in[7];
  const float* cl1w  = (const float*)d_in[8];
  const float* cl2w  = (const float*)d_in[9];
  const float* cl2b  = (const float*)d_in[10];
  const float* linw  = (const float*)d_in[11];
  const float* linb  = (const float*)d_in[12];
  const float* o1w   = (const float*)d_in[13];
  const float* o1b   = (const float*)d_in[14];
  const float* o2w   = (const float*)d_in[15];
  const float* o2b   = (const float*)d_in[16];
  float* out = (float*)d_out;

  char* ws = (char*)d_ws;
  size_t off = 0;
  float* h_cur = (float*)(ws + off); off += (size_t)N_NODES*HID*4;
  float* agg   = (float*)(ws + off); off += (size_t)N_NODES*NF*4;
  float* dist  = (float*)(ws + off); off += (size_t)N_EDGES*4;
  float* csr_d = (float*)(ws + off); off += (size_t)N_EDGES*4;
  u16*   hxb   = (u16*)  (ws + off); off += (size_t)N_NODES*NF*2;
  u16*   tabi  = (u16*)  (ws + off); off += (size_t)NL*TAB*NF*2*2;
  int* csr_src   = (int*)(ws + off); off += (size_t)N_EDGES*4;
  int* deg       = (int*)(ws + off); off += (size_t)N_NODES*4;
  int* row_start = (int*)(ws + off); off += (size_t)(N_NODES + 64)*4;
  int* cursor    = (int*)(ws + off); off += (size_t)N_NODES*4;

  hipMemsetAsync(out, 0, NSEG*sizeof(float), stream);
  hipMemsetAsync(deg, 0, N_NODES*sizeof(int), stream);
  hipMemsetAsync(cursor, 0, N_NODES*sizeof(int), stream);
  hipMemcpyAsync(h_cur, h, (size_t)N_NODES*HID*sizeof(float), hipMemcpyDeviceToDevice, stream);

  k_dist<<<2048, 256, 0, stream>>>(ei, pos, dist, deg);
  k_scan<<<1, 1024, 0, stream>>>(deg, row_start);
  k_scatter<<<2048, 256, 0, stream>>>(ei, dist, row_start, cursor, csr_src, csr_d);
  k_table<<<NL*TAB, 128, 0, stream>>>(mlp_w1, mlp_b1, mlp_w2, mlp_b2, tabi);

  k_lin1b<<<N_NODES/8, 128, 0, stream>>>(h_cur, cl1w, hxb);
  for (int l = 0; l < NL; l++){
    k_edgeagg<<<N_NODES/4, 256, 0, stream>>>(row_start, csr_src, csr_d,
                                             tabi + (size_t)l*TAB*NF*2, hxb, agg);
    const float* w1n = (l + 1 < NL) ? (cl1w + (size_t)(l+1)*HID*NF) : nullptr;
    k_nodefuse<<<N_NODES/8, 128, 0, stream>>>(agg, cl2w + (size_t)l*NF*HID, cl2b + (size_t)l*HID,
                                              linw + (size_t)l*HID*HID, linb + (size_t)l*HID,
                                              h_cur, w1n, hxb);
  }
  k_out<<<256, 256, 0, stream>>>(h_cur, o1w, o1b, o2w, o2b, batch, out);
}

// Round 4
// 1752.813 us; speedup vs baseline: 2.2280x; 2.2280x over previous
//
#include <hip/hip_runtime.h>
#include <math.h>

#define N_NODES 50000
#define N_EDGES 1600000
#define HID 128
#define NF 128
#define NG 50
#define NL 6
#define NSEG 64
#define TAB 2048
#define CUTOFF 20.0f
#define LOG2F_ 0.6931471805599453f

typedef unsigned short u16;
typedef __attribute__((ext_vector_type(8))) short short8;   // 8 bf16 (4 VGPRs) MFMA A/B frag
typedef __attribute__((ext_vector_type(4))) float f32x4;    // MFMA C/D frag

__device__ __forceinline__ float ssp(float x){
  float sp = fmaxf(x, 0.f) + log1pf(expf(-fabsf(x)));
  return sp - LOG2F_;
}
__device__ __forceinline__ float b2f(u16 u){
  unsigned v = ((unsigned)u) << 16; float f; __builtin_memcpy(&f, &v, 4); return f;
}
__device__ __forceinline__ u16 f2b(float f){
  unsigned u; __builtin_memcpy(&u, &f, 4);
  u += 0x7FFFu + ((u >> 16) & 1u);
  return (u16)(u >> 16);
}
// XOR-swizzled byte offset within a [16][128] bf16 tile (256B rows).
// Spreads the 16 row-parallel 16B reads across all banks (T2).
__device__ __forceinline__ int swz(int row, int colb){
  return row*256 + (colb ^ ((row & 15) << 4));
}

// ---------------- edge distance + degree histogram (fused) ----------------
__global__ __launch_bounds__(256) void k_dist(const int* __restrict__ ei,
                                              const float* __restrict__ pos,
                                              float* __restrict__ dist,
                                              int* __restrict__ deg){
  for (int e = blockIdx.x*blockDim.x + threadIdx.x; e < N_EDGES; e += gridDim.x*blockDim.x){
    int s = ei[e], t = ei[N_EDGES + e];
    float dx = pos[3*s]   - pos[3*t];
    float dy = pos[3*s+1] - pos[3*t+1];
    float dz = pos[3*s+2] - pos[3*t+2];
    dist[e] = sqrtf(dx*dx + dy*dy + dz*dz);
    atomicAdd(&deg[t], 1);
  }
}

__global__ __launch_bounds__(1024) void k_scan(const int* __restrict__ deg, int* __restrict__ row_start){
  __shared__ int sums[1024];
  const int t = threadIdx.x;
  const int CH = (N_NODES + 1023) / 1024; // 49
  const int base = t * CH;
  int s = 0;
  for (int i = 0; i < CH; i++){ int idx = base + i; if (idx < N_NODES) s += deg[idx]; }
  sums[t] = s; __syncthreads();
  for (int off = 1; off < 1024; off <<= 1){
    int v = (t >= off) ? sums[t - off] : 0;
    __syncthreads();
    sums[t] += v;
    __syncthreads();
  }
  int run = (t == 0) ? 0 : sums[t - 1];
  for (int i = 0; i < CH; i++){
    int idx = base + i;
    if (idx < N_NODES){ row_start[idx] = run; run += deg[idx]; }
  }
  if (t == 1023) row_start[N_NODES] = run;
}

__global__ __launch_bounds__(256) void k_scatter(const int* __restrict__ ei,
                                                 const float* __restrict__ dist,
                                                 const int* __restrict__ row_start,
                                                 int* __restrict__ cursor,
                                                 int* __restrict__ csr_src,
                                                 float* __restrict__ csr_d){
  for (int e = blockIdx.x*blockDim.x + threadIdx.x; e < N_EDGES; e += gridDim.x*blockDim.x){
    int dn = ei[N_EDGES + e];
    int slot = atomicAdd(&cursor[dn], 1);
    int p = row_start[dn] + slot;
    csr_src[p] = ei[e];
    csr_d[p]   = dist[e];
  }
}

// ---------------- filter table: W_l(d)*C(d), bf16, rows j and j+1 interleaved ----------------
__global__ __launch_bounds__(128) void k_table(const float* __restrict__ w1, const float* __restrict__ b1,
                                               const float* __restrict__ w2, const float* __restrict__ b2,
                                               u16* __restrict__ tabi){
  int l = blockIdx.x / TAB, j = blockIdx.x % TAB;
  int tid = threadIdx.x;
  float d = j * (CUTOFF / (TAB - 1));
  __shared__ float ea[NG];
  __shared__ float sbuf[NF];
  if (tid < NG){
    const float gstep = CUTOFF / (NG - 1);
    const float coeff = -0.5f / (gstep * gstep);
    float u = d - tid * gstep;
    ea[tid] = expf(coeff * u * u);
  }
  __syncthreads();
  float z = b1[l*NF + tid];
  for (int k = 0; k < NG; k++) z += ea[k] * w1[(l*NG + k)*NF + tid];
  sbuf[tid] = ssp(z);
  __syncthreads();
  float W = b2[l*NF + tid];
  for (int k = 0; k < NF; k++) W += sbuf[k] * w2[(l*NF + k)*NF + tid];
  float C = 0.5f * (cosf(d * (float)M_PI / CUTOFF) + 1.f);
  u16 wb = f2b(W * C);
  tabi[(((size_t)l*TAB + j)*NF + tid)*2] = wb;
  if (j > 0)        tabi[(((size_t)l*TAB + j - 1)*NF + tid)*2 + 1] = wb;
  if (j == TAB - 1) tabi[(((size_t)l*TAB + j)*NF + tid)*2 + 1] = wb;
}

// ---------------- weight convert: [in][out] fp32 -> [out][in] bf16 ----------------
__global__ __launch_bounds__(128) void k_wconv(const float* __restrict__ w, u16* __restrict__ wT){
  int m = blockIdx.x >> 7, o = blockIdx.x & 127;
  int i = threadIdx.x;
  wT[((size_t)m*128 + o)*128 + i] = f2b(w[((size_t)m*128 + i)*128 + o]);
}

// ---------------- layer-0 lin1: hxb = bf16(h @ w1) via MFMA ----------------
__global__ __launch_bounds__(256) void k_lin1m(const float* __restrict__ h,
                                               const u16* __restrict__ w1T,
                                               u16* __restrict__ hxb){
  int tid = threadIdx.x;
  int wv = tid >> 6, l = tid & 63;
  int n0 = blockIdx.x * 64 + wv * 16;
  if (n0 >= N_NODES) return;
  int li = l & 15, lh = l >> 4;
  __shared__ u16 tiles[4][16*128];
  char* tb = (char*)&tiles[wv][0];

  short8 a[4];
  #pragma unroll
  for (int kc = 0; kc < 4; kc++){
    const float* p = &h[(size_t)(n0 + li)*HID + kc*32 + lh*8];
    union { short8 v; u16 u[8]; } t;
    #pragma unroll
    for (int e = 0; e < 8; e++) t.u[e] = f2b(p[e]);
    a[kc] = t.v;
  }
  #pragma unroll
  for (int fc = 0; fc < 8; fc++){
    f32x4 acc = {0.f,0.f,0.f,0.f};
    #pragma unroll
    for (int kc = 0; kc < 4; kc++){
      short8 b = *(const short8*)&w1T[(size_t)(fc*16 + li)*HID + kc*32 + lh*8];
      acc = __builtin_amdgcn_mfma_f32_16x16x32_bf16(a[kc], b, acc, 0, 0, 0);
    }
    #pragma unroll
    for (int r = 0; r < 4; r++)
      *(u16*)(tb + swz(lh*4 + r, fc*32 + li*2)) = f2b(acc[r]);
  }
  #pragma unroll
  for (int g = 0; g < 4; g++){
    int row = g*4 + lh;
    short8 v = *(const short8*)(tb + swz(row, li*16));
    *(short8*)&hxb[(size_t)(n0 + row)*NF + li*8] = v;
  }
}

// ---------------- edge aggregation: one wave per node, bf16 gathers, bf16 out ----------------
__global__ __launch_bounds__(256) void k_edgeagg(const int* __restrict__ row_start,
                                                 const int* __restrict__ csr_src,
                                                 const float* __restrict__ csr_d,
                                                 const u16* __restrict__ tabi_l,
                                                 const u16* __restrict__ hxb,
                                                 u16* __restrict__ aggb){
  int wave = threadIdx.x >> 6, lane = threadIdx.x & 63;
  int i = blockIdx.x * 4 + wave;
  int rs = row_start[i], re = row_start[i + 1];
  const float INV_STEP = (TAB - 1) / CUTOFF;
  float acc0 = 0.f, acc1 = 0.f;
  for (int p = rs; p < re; ++p){
    int s = csr_src[p];
    float dv = csr_d[p];
    float t = dv * INV_STEP;
    t = fminf(fmaxf(t, 0.f), (float)(TAB - 1) - 0.001f);
    int i0 = (int)t;
    float fr = t - (float)i0;
    ushort2 hv = *(const ushort2*)&hxb[(size_t)s * NF + 2*lane];
    ushort4 wv = *(const ushort4*)&tabi_l[((size_t)i0 * NF + 2*lane)*2];
    float w00 = b2f(wv.x), w01 = b2f(wv.y);
    float w10 = b2f(wv.z), w11 = b2f(wv.w);
    float W0 = w00 + fr * (w01 - w00);
    float W1 = w10 + fr * (w11 - w10);
    acc0 += b2f(hv.x) * W0;
    acc1 += b2f(hv.y) * W1;
  }
  ushort2 o; o.x = f2b(acc0); o.y = f2b(acc1);
  *(ushort2*)&aggb[(size_t)i * NF + 2*lane] = o;
}

// ---------------- fused node update via MFMA ----------------
// z = aggb@w2 + b2 ; s = ssp(z) ; h += s@lin + linb ; hxb = bf16(h@w1n)
__global__ __launch_bounds__(256) void k_nodefuse(const u16* __restrict__ aggb,
                                                  const u16* __restrict__ w2T, const float* __restrict__ b2b,
                                                  const u16* __restrict__ lT,  const float* __restrict__ linb,
                                                  float* __restrict__ h,
                                                  const u16* __restrict__ w1nT,
                                                  u16* __restrict__ hxb){
  int tid = threadIdx.x;
  int wv = tid >> 6, l = tid & 63;
  int n0 = blockIdx.x * 64 + wv * 16;
  if (n0 >= N_NODES) return;
  int li = l & 15, lh = l >> 4;
  __shared__ u16 tiles[4][16*128];
  char* tb = (char*)&tiles[wv][0];

  // A-frags from aggb (bf16)
  short8 a[4];
  #pragma unroll
  for (int kc = 0; kc < 4; kc++)
    a[kc] = *(const short8*)&aggb[(size_t)(n0 + li)*NF + kc*32 + lh*8];

  // GEMM1: z = agg@w2 + b2 ; s = ssp(z) -> s_tile (swizzled)
  #pragma unroll
  for (int fc = 0; fc < 8; fc++){
    f32x4 acc = {0.f,0.f,0.f,0.f};
    #pragma unroll
    for (int kc = 0; kc < 4; kc++){
      short8 b = *(const short8*)&w2T[(size_t)(fc*16 + li)*NF + kc*32 + lh*8];
      acc = __builtin_amdgcn_mfma_f32_16x16x32_bf16(a[kc], b, acc, 0, 0, 0);
    }
    float bias = b2b[fc*16 + li];
    #pragma unroll
    for (int r = 0; r < 4; r++){
      float s = ssp(acc[r] + bias);
      *(u16*)(tb + swz(lh*4 + r, fc*32 + li*2)) = f2b(s);
    }
  }

  // A2-frags from s_tile
  short8 a2[4];
  #pragma unroll
  for (int kc = 0; kc < 4; kc++)
    a2[kc] = *(const short8*)(tb + swz(li, kc*64 + lh*16));

  // GEMM2: delta = s@lin + linb ; h += delta ; h_new -> tile (for GEMM3)
  #pragma unroll
  for (int fc = 0; fc < 8; fc++){
    f32x4 acc = {0.f,0.f,0.f,0.f};
    #pragma unroll
    for (int kc = 0; kc < 4; kc++){
      short8 b = *(const short8*)&lT[(size_t)(fc*16 + li)*HID + kc*32 + lh*8];
      acc = __builtin_amdgcn_mfma_f32_16x16x32_bf16(a2[kc], b, acc, 0, 0, 0);
    }
    float bias = linb[fc*16 + li];
    #pragma unroll
    for (int r = 0; r < 4; r++){
      int i = lh*4 + r;
      size_t off = (size_t)(n0 + i)*HID + fc*16 + li;
      float hn = h[off] + acc[r] + bias;
      h[off] = hn;
      if (w1nT) *(u16*)(tb + swz(i, fc*32 + li*2)) = f2b(hn);
    }
  }
  if (!w1nT) return;

  // GEMM3: hx_next = bf16(h_new @ w1n)
  short8 a3[4];
  #pragma unroll
  for (int kc = 0; kc < 4; kc++)
    a3[kc] = *(const short8*)(tb + swz(li, kc*64 + lh*16));
  #pragma unroll
  for (int fc = 0; fc < 8; fc++){
    f32x4 acc = {0.f,0.f,0.f,0.f};
    #pragma unroll
    for (int kc = 0; kc < 4; kc++){
      short8 b = *(const short8*)&w1nT[(size_t)(fc*16 + li)*HID + kc*32 + lh*8];
      acc = __builtin_amdgcn_mfma_f32_16x16x32_bf16(a3[kc], b, acc, 0, 0, 0);
    }
    #pragma unroll
    for (int r = 0; r < 4; r++)
      *(u16*)(tb + swz(lh*4 + r, fc*32 + li*2)) = f2b(acc[r]);
  }
  #pragma unroll
  for (int g = 0; g < 4; g++){
    int row = g*4 + lh;
    short8 v = *(const short8*)(tb + swz(row, li*16));
    *(short8*)&hxb[(size_t)(n0 + row)*NF + li*8] = v;
  }
}

// ---------------- readout: contiguous chunk per wave, run-length segment sum ----------------
__global__ __launch_bounds__(256) void k_out(const float* __restrict__ h,
                                             const float* __restrict__ w1, const float* __restrict__ b1,
                                             const float* __restrict__ w2, const float* __restrict__ b2,
                                             const int* __restrict__ batch, float* __restrict__ out){
  __shared__ float w1s[HID * 64];
  int tid = threadIdx.x;
  for (int k = tid; k < HID * 64; k += 256) w1s[k] = w1[k];
  __syncthreads();
  int wave = tid >> 6, lane = tid & 63;
  int gwave = blockIdx.x * 4 + wave;
  const int NWAVES = 256 * 4;
  const int CHUNK = (N_NODES + NWAVES - 1) / NWAVES; // 49
  int n0 = gwave * CHUNK;
  int n1 = n0 + CHUNK; if (n1 > N_NODES) n1 = N_NODES;
  float b1v = b1[lane];
  float w2v = w2[lane];
  float b2v = b2[0];
  float run = 0.f; int curseg = -1;
  for (int n = n0; n < n1; ++n){
    float h0 = h[(size_t)n * HID + lane];
    float h1 = h[(size_t)n * HID + 64 + lane];
    float acc = b1v;
    #pragma unroll
    for (int k = 0; k < 64; k++){
      float hb = __shfl(h0, k);
      acc += hb * w1s[k * 64 + lane];
    }
    #pragma unroll
    for (int k = 0; k < 64; k++){
      float hb = __shfl(h1, k);
      acc += hb * w1s[(64 + k) * 64 + lane];
    }
    float p = ssp(acc) * w2v;
    #pragma unroll
    for (int off = 32; off >= 1; off >>= 1) p += __shfl_xor(p, off);
    if (lane == 0){
      int seg = batch[n];
      if (seg != curseg){
        if (curseg >= 0) atomicAdd(&out[curseg], run);
        curseg = seg; run = 0.f;
      }
      run += p + b2v;
    }
  }
  if (lane == 0 && curseg >= 0) atomicAdd(&out[curseg], run);
}

extern "C" void kernel_launch(void* const* d_in, const int* in_sizes, int n_in,
                              void* d_out, int out_size, void* d_ws, size_t ws_size,
                              hipStream_t stream) {
  const float* h     = (const float*)d_in[0];
  const float* pos   = (const float*)d_in[1];
  const int*   ei    = (const int*)d_in[2];
  const int*   batch = (const int*)d_in[3];
  const float* mlp_w1 = (const float*)d_in[4];
  const float* mlp_b1 = (const float*)d_in[5];
  const float* mlp_w2 = (const float*)d_in[6];
  const float* mlp_b2 = (const float*)d_in[7];
  const float* cl1w  = (const float*)d_in[8];
  const float* cl2w  = (const float*)d_in[9];
  const float* cl2b  = (const float*)d_in[10];
  const float* linw  = (const float*)d_in[11];
  const float* linb  = (const float*)d_in[12];
  const float* o1w   = (const float*)d_in[13];
  const float* o1b   = (const float*)d_in[14];
  const float* o2w   = (const float*)d_in[15];
  const float* o2b   = (const float*)d_in[16];
  float* out = (float*)d_out;

  char* ws = (char*)d_ws;
  size_t off = 0;
  float* h_cur = (float*)(ws + off); off += (size_t)N_NODES*HID*4;
  float* dist  = (float*)(ws + off); off += (size_t)N_EDGES*4;
  float* csr_d = (float*)(ws + off); off += (size_t)N_EDGES*4;
  u16*   aggb  = (u16*)  (ws + off); off += (size_t)N_NODES*NF*2;
  u16*   hxb   = (u16*)  (ws + off); off += (size_t)N_NODES*NF*2;
  u16*   tabi  = (u16*)  (ws + off); off += (size_t)NL*TAB*NF*2*2;
  u16*   w1T   = (u16*)  (ws + off); off += (size_t)NL*HID*NF*2;
  u16*   w2T   = (u16*)  (ws + off); off += (size_t)NL*NF*HID*2;
  u16*   lT    = (u16*)  (ws + off); off += (size_t)NL*HID*HID*2;
  int* csr_src   = (int*)(ws + off); off += (size_t)N_EDGES*4;
  int* deg       = (int*)(ws + off); off += (size_t)N_NODES*4;
  int* row_start = (int*)(ws + off); off += (size_t)(N_NODES + 64)*4;
  int* cursor    = (int*)(ws + off); off += (size_t)N_NODES*4;

  hipMemsetAsync(out, 0, NSEG*sizeof(float), stream);
  hipMemsetAsync(deg, 0, N_NODES*sizeof(int), stream);
  hipMemsetAsync(cursor, 0, N_NODES*sizeof(int), stream);
  hipMemcpyAsync(h_cur, h, (size_t)N_NODES*HID*sizeof(float), hipMemcpyDeviceToDevice, stream);

  k_dist<<<2048, 256, 0, stream>>>(ei, pos, dist, deg);
  k_scan<<<1, 1024, 0, stream>>>(deg, row_start);
  k_scatter<<<2048, 256, 0, stream>>>(ei, dist, row_start, cursor, csr_src, csr_d);
  k_table<<<NL*TAB, 128, 0, stream>>>(mlp_w1, mlp_b1, mlp_w2, mlp_b2, tabi);
  k_wconv<<<NL*128, 128, 0, stream>>>(cl1w, w1T);
  k_wconv<<<NL*128, 128, 0, stream>>>(cl2w, w2T);
  k_wconv<<<NL*128, 128, 0, stream>>>(linw, lT);

  const int NBLK = (N_NODES + 63) / 64; // 782
  k_lin1m<<<NBLK, 256, 0, stream>>>(h_cur, w1T, hxb);
  for (int l = 0; l < NL; l++){
    k_edgeagg<<<N_NODES/4, 256, 0, stream>>>(row_start, csr_src, csr_d,
                                             tabi + (size_t)l*TAB*NF*2, hxb, aggb);
    const u16* w1n = (l + 1 < NL) ? (w1T + (size_t)(l+1)*HID*NF) : nullptr;
    k_nodefuse<<<NBLK, 256, 0, stream>>>(aggb, w2T + (size_t)l*NF*HID, cl2b + (size_t)l*HID,
                                         lT + (size_t)l*HID*HID, linb + (size_t)l*HID,
                                         h_cur, w1n, hxb);
  }
  k_out<<<256, 256, 0, stream>>>(h_cur, o1w, o1b, o2w, o2b, batch, out);
}

// Round 5
// 1138.430 us; speedup vs baseline: 3.4304x; 1.5397x over previous
//
#include <hip/hip_runtime.h>
#include <math.h>

#define N_NODES 50000
#define N_EDGES 1600000
#define HID 128
#define NF 128
#define NG 50
#define NL 6
#define NSEG 64
#define TAB2 4096
#define CUTOFF 20.0f
#define LOG2F_ 0.6931471805599453f

typedef unsigned short u16;
typedef __attribute__((ext_vector_type(8))) short short8;            // 8 bf16 MFMA A/B frag
typedef __attribute__((ext_vector_type(8))) unsigned short ushort8;  // 16B bf16 load
typedef __attribute__((ext_vector_type(4))) float f32x4;             // MFMA C/D frag

__device__ __forceinline__ float ssp(float x){
  float sp = fmaxf(x, 0.f) + log1pf(expf(-fabsf(x)));
  return sp - LOG2F_;
}
__device__ __forceinline__ float b2f(u16 u){
  unsigned v = ((unsigned)u) << 16; float f; __builtin_memcpy(&f, &v, 4); return f;
}
__device__ __forceinline__ u16 f2b(float f){
  unsigned u; __builtin_memcpy(&u, &f, 4);
  u += 0x7FFFu + ((u >> 16) & 1u);
  return (u16)(u >> 16);
}
// XOR-swizzled byte offset within a [16][128] bf16 tile (256B rows).
__device__ __forceinline__ int swz(int row, int colb){
  return row*256 + (colb ^ ((row & 15) << 4));
}

// ---------------- edge distance + degree histogram (fused) ----------------
__global__ __launch_bounds__(256) void k_dist(const int* __restrict__ ei,
                                              const float* __restrict__ pos,
                                              float* __restrict__ dist,
                                              int* __restrict__ deg){
  for (int e = blockIdx.x*blockDim.x + threadIdx.x; e < N_EDGES; e += gridDim.x*blockDim.x){
    int s = ei[e], t = ei[N_EDGES + e];
    float dx = pos[3*s]   - pos[3*t];
    float dy = pos[3*s+1] - pos[3*t+1];
    float dz = pos[3*s+2] - pos[3*t+2];
    dist[e] = sqrtf(dx*dx + dy*dy + dz*dz);
    atomicAdd(&deg[t], 1);
  }
}

__global__ __launch_bounds__(1024) void k_scan(const int* __restrict__ deg, int* __restrict__ row_start){
  __shared__ int sums[1024];
  const int t = threadIdx.x;
  const int CH = (N_NODES + 1023) / 1024; // 49
  const int base = t * CH;
  int s = 0;
  for (int i = 0; i < CH; i++){ int idx = base + i; if (idx < N_NODES) s += deg[idx]; }
  sums[t] = s; __syncthreads();
  for (int off = 1; off < 1024; off <<= 1){
    int v = (t >= off) ? sums[t - off] : 0;
    __syncthreads();
    sums[t] += v;
    __syncthreads();
  }
  int run = (t == 0) ? 0 : sums[t - 1];
  for (int i = 0; i < CH; i++){
    int idx = base + i;
    if (idx < N_NODES){ row_start[idx] = run; run += deg[idx]; }
  }
  if (t == 1023) row_start[N_NODES] = run;
}

// pack (table_index<<16 | src) per CSR slot
__global__ __launch_bounds__(256) void k_scatter(const int* __restrict__ ei,
                                                 const float* __restrict__ dist,
                                                 const int* __restrict__ row_start,
                                                 int* __restrict__ cursor,
                                                 unsigned* __restrict__ csr_pack){
  const float INV_STEP = (TAB2 - 1) / CUTOFF;
  for (int e = blockIdx.x*blockDim.x + threadIdx.x; e < N_EDGES; e += gridDim.x*blockDim.x){
    int dn = ei[N_EDGES + e];
    int slot = atomicAdd(&cursor[dn], 1);
    int p = row_start[dn] + slot;
    int j = (int)(dist[e] * INV_STEP + 0.5f);
    if (j > TAB2 - 1) j = TAB2 - 1;
    csr_pack[p] = ((unsigned)j << 16) | (unsigned)ei[e];
  }
}

// ---------------- filter table: W_l(d)*C(d), bf16, plain [l][j][f] ----------------
__global__ __launch_bounds__(128) void k_table(const float* __restrict__ w1, const float* __restrict__ b1,
                                               const float* __restrict__ w2, const float* __restrict__ b2,
                                               u16* __restrict__ tab){
  int l = blockIdx.x / TAB2, j = blockIdx.x % TAB2;
  int tid = threadIdx.x;
  float d = j * (CUTOFF / (TAB2 - 1));
  __shared__ float ea[NG];
  __shared__ float sbuf[NF];
  if (tid < NG){
    const float gstep = CUTOFF / (NG - 1);
    const float coeff = -0.5f / (gstep * gstep);
    float u = d - tid * gstep;
    ea[tid] = expf(coeff * u * u);
  }
  __syncthreads();
  float z = b1[l*NF + tid];
  for (int k = 0; k < NG; k++) z += ea[k] * w1[(l*NG + k)*NF + tid];
  sbuf[tid] = ssp(z);
  __syncthreads();
  float W = b2[l*NF + tid];
  for (int k = 0; k < NF; k++) W += sbuf[k] * w2[(l*NF + k)*NF + tid];
  float C = 0.5f * (cosf(d * (float)M_PI / CUTOFF) + 1.f);
  tab[((size_t)l*TAB2 + j)*NF + tid] = f2b(W * C);
}

// ---------------- weight convert: [in][out] fp32 -> [out][in] bf16 ----------------
__global__ __launch_bounds__(128) void k_wconv(const float* __restrict__ w, u16* __restrict__ wT){
  int m = blockIdx.x >> 7, o = blockIdx.x & 127;
  int i = threadIdx.x;
  wT[((size_t)m*128 + o)*128 + i] = f2b(w[((size_t)m*128 + i)*128 + o]);
}

// ---------------- layer-0 lin1: hxb = bf16(h @ w1) via MFMA ----------------
__global__ __launch_bounds__(256) void k_lin1m(const float* __restrict__ h,
                                               const u16* __restrict__ w1T,
                                               u16* __restrict__ hxb){
  int tid = threadIdx.x;
  int wv = tid >> 6, l = tid & 63;
  int n0 = blockIdx.x * 64 + wv * 16;
  if (n0 >= N_NODES) return;
  int li = l & 15, lh = l >> 4;
  __shared__ u16 tiles[4][16*128];
  char* tb = (char*)&tiles[wv][0];

  short8 a[4];
  #pragma unroll
  for (int kc = 0; kc < 4; kc++){
    const float* p = &h[(size_t)(n0 + li)*HID + kc*32 + lh*8];
    union { short8 v; u16 u[8]; } t;
    #pragma unroll
    for (int e = 0; e < 8; e++) t.u[e] = f2b(p[e]);
    a[kc] = t.v;
  }
  #pragma unroll
  for (int fc = 0; fc < 8; fc++){
    f32x4 acc = {0.f,0.f,0.f,0.f};
    #pragma unroll
    for (int kc = 0; kc < 4; kc++){
      short8 b = *(const short8*)&w1T[(size_t)(fc*16 + li)*HID + kc*32 + lh*8];
      acc = __builtin_amdgcn_mfma_f32_16x16x32_bf16(a[kc], b, acc, 0, 0, 0);
    }
    #pragma unroll
    for (int r = 0; r < 4; r++)
      *(u16*)(tb + swz(lh*4 + r, fc*32 + li*2)) = f2b(acc[r]);
  }
  #pragma unroll
  for (int g = 0; g < 4; g++){
    int row = g*4 + lh;
    short8 v = *(const short8*)(tb + swz(row, li*16));
    *(short8*)&hxb[(size_t)(n0 + row)*NF + li*8] = v;
  }
}

// ---------------- edge aggregation: 4 edges/wave-iter, 16 lanes/edge, 8 feat/lane ----------------
__global__ __launch_bounds__(256) void k_edgeagg(const int* __restrict__ row_start,
                                                 const unsigned* __restrict__ csr_pack,
                                                 const u16* __restrict__ tab_l,
                                                 const u16* __restrict__ hxb,
                                                 u16* __restrict__ aggb){
  int wave = threadIdx.x >> 6, lane = threadIdx.x & 63;
  int i = blockIdx.x * 4 + wave;
  int li = lane & 15, g = lane >> 4;
  int rs = row_start[i], re = row_start[i + 1];
  float acc[8];
  #pragma unroll
  for (int r = 0; r < 8; r++) acc[r] = 0.f;
  for (int p = rs + g; p < re; p += 4){
    unsigned v = csr_pack[p];
    int s = (int)(v & 0xFFFFu);
    int j = (int)(v >> 16);
    ushort8 hv = *(const ushort8*)&hxb[(size_t)s * NF + li*8];
    ushort8 wv = *(const ushort8*)&tab_l[(size_t)j * NF + li*8];
    #pragma unroll
    for (int r = 0; r < 8; r++)
      acc[r] += b2f(hv[r]) * b2f(wv[r]);
  }
  #pragma unroll
  for (int r = 0; r < 8; r++){
    acc[r] += __shfl_xor(acc[r], 16);
    acc[r] += __shfl_xor(acc[r], 32);
  }
  if (g == 0){
    union { short8 v; u16 u[8]; } o;
    #pragma unroll
    for (int r = 0; r < 8; r++) o.u[r] = f2b(acc[r]);
    *(short8*)&aggb[(size_t)i * NF + li*8] = o.v;
  }
}

// ---------------- fused node update via MFMA ----------------
__global__ __launch_bounds__(256) void k_nodefuse(const u16* __restrict__ aggb,
                                                  const u16* __restrict__ w2T, const float* __restrict__ b2b,
                                                  const u16* __restrict__ lT,  const float* __restrict__ linb,
                                                  float* __restrict__ h,
                                                  const u16* __restrict__ w1nT,
                                                  u16* __restrict__ hxb){
  int tid = threadIdx.x;
  int wv = tid >> 6, l = tid & 63;
  int n0 = blockIdx.x * 64 + wv * 16;
  if (n0 >= N_NODES) return;
  int li = l & 15, lh = l >> 4;
  __shared__ u16 tiles[4][16*128];
  char* tb = (char*)&tiles[wv][0];

  short8 a[4];
  #pragma unroll
  for (int kc = 0; kc < 4; kc++)
    a[kc] = *(const short8*)&aggb[(size_t)(n0 + li)*NF + kc*32 + lh*8];

  #pragma unroll
  for (int fc = 0; fc < 8; fc++){
    f32x4 acc = {0.f,0.f,0.f,0.f};
    #pragma unroll
    for (int kc = 0; kc < 4; kc++){
      short8 b = *(const short8*)&w2T[(size_t)(fc*16 + li)*NF + kc*32 + lh*8];
      acc = __builtin_amdgcn_mfma_f32_16x16x32_bf16(a[kc], b, acc, 0, 0, 0);
    }
    float bias = b2b[fc*16 + li];
    #pragma unroll
    for (int r = 0; r < 4; r++){
      float s = ssp(acc[r] + bias);
      *(u16*)(tb + swz(lh*4 + r, fc*32 + li*2)) = f2b(s);
    }
  }

  short8 a2[4];
  #pragma unroll
  for (int kc = 0; kc < 4; kc++)
    a2[kc] = *(const short8*)(tb + swz(li, kc*64 + lh*16));

  #pragma unroll
  for (int fc = 0; fc < 8; fc++){
    f32x4 acc = {0.f,0.f,0.f,0.f};
    #pragma unroll
    for (int kc = 0; kc < 4; kc++){
      short8 b = *(const short8*)&lT[(size_t)(fc*16 + li)*HID + kc*32 + lh*8];
      acc = __builtin_amdgcn_mfma_f32_16x16x32_bf16(a2[kc], b, acc, 0, 0, 0);
    }
    float bias = linb[fc*16 + li];
    #pragma unroll
    for (int r = 0; r < 4; r++){
      int i = lh*4 + r;
      size_t off = (size_t)(n0 + i)*HID + fc*16 + li;
      float hn = h[off] + acc[r] + bias;
      h[off] = hn;
      if (w1nT) *(u16*)(tb + swz(i, fc*32 + li*2)) = f2b(hn);
    }
  }
  if (!w1nT) return;

  short8 a3[4];
  #pragma unroll
  for (int kc = 0; kc < 4; kc++)
    a3[kc] = *(const short8*)(tb + swz(li, kc*64 + lh*16));
  #pragma unroll
  for (int fc = 0; fc < 8; fc++){
    f32x4 acc = {0.f,0.f,0.f,0.f};
    #pragma unroll
    for (int kc = 0; kc < 4; kc++){
      short8 b = *(const short8*)&w1nT[(size_t)(fc*16 + li)*HID + kc*32 + lh*8];
      acc = __builtin_amdgcn_mfma_f32_16x16x32_bf16(a3[kc], b, acc, 0, 0, 0);
    }
    #pragma unroll
    for (int r = 0; r < 4; r++)
      *(u16*)(tb + swz(lh*4 + r, fc*32 + li*2)) = f2b(acc[r]);
  }
  #pragma unroll
  for (int g = 0; g < 4; g++){
    int row = g*4 + lh;
    short8 v = *(const short8*)(tb + swz(row, li*16));
    *(short8*)&hxb[(size_t)(n0 + row)*NF + li*8] = v;
  }
}

// ---------------- readout ----------------
__global__ __launch_bounds__(256) void k_out(const float* __restrict__ h,
                                             const float* __restrict__ w1, const float* __restrict__ b1,
                                             const float* __restrict__ w2, const float* __restrict__ b2,
                                             const int* __restrict__ batch, float* __restrict__ out){
  __shared__ float w1s[HID * 64];
  int tid = threadIdx.x;
  for (int k = tid; k < HID * 64; k += 256) w1s[k] = w1[k];
  __syncthreads();
  int wave = tid >> 6, lane = tid & 63;
  int gwave = blockIdx.x * 4 + wave;
  const int NWAVES = 256 * 4;
  const int CHUNK = (N_NODES + NWAVES - 1) / NWAVES; // 49
  int n0 = gwave * CHUNK;
  int n1 = n0 + CHUNK; if (n1 > N_NODES) n1 = N_NODES;
  float b1v = b1[lane];
  float w2v = w2[lane];
  float b2v = b2[0];
  float run = 0.f; int curseg = -1;
  for (int n = n0; n < n1; ++n){
    float h0 = h[(size_t)n * HID + lane];
    float h1 = h[(size_t)n * HID + 64 + lane];
    float acc = b1v;
    #pragma unroll
    for (int k = 0; k < 64; k++){
      float hb = __shfl(h0, k);
      acc += hb * w1s[k * 64 + lane];
    }
    #pragma unroll
    for (int k = 0; k < 64; k++){
      float hb = __shfl(h1, k);
      acc += hb * w1s[(64 + k) * 64 + lane];
    }
    float p = ssp(acc) * w2v;
    #pragma unroll
    for (int off = 32; off >= 1; off >>= 1) p += __shfl_xor(p, off);
    if (lane == 0){
      int seg = batch[n];
      if (seg != curseg){
        if (curseg >= 0) atomicAdd(&out[curseg], run);
        curseg = seg; run = 0.f;
      }
      run += p + b2v;
    }
  }
  if (lane == 0 && curseg >= 0) atomicAdd(&out[curseg], run);
}

extern "C" void kernel_launch(void* const* d_in, const int* in_sizes, int n_in,
                              void* d_out, int out_size, void* d_ws, size_t ws_size,
                              hipStream_t stream) {
  const float* h     = (const float*)d_in[0];
  const float* pos   = (const float*)d_in[1];
  const int*   ei    = (const int*)d_in[2];
  const int*   batch = (const int*)d_in[3];
  const float* mlp_w1 = (const float*)d_in[4];
  const float* mlp_b1 = (const float*)d_in[5];
  const float* mlp_w2 = (const float*)d_in[6];
  const float* mlp_b2 = (const float*)d_in[7];
  const float* cl1w  = (const float*)d_in[8];
  const float* cl2w  = (const float*)d_in[9];
  const float* cl2b  = (const float*)d_in[10];
  const float* linw  = (const float*)d_in[11];
  const float* linb  = (const float*)d_in[12];
  const float* o1w   = (const float*)d_in[13];
  const float* o1b   = (const float*)d_in[14];
  const float* o2w   = (const float*)d_in[15];
  const float* o2b   = (const float*)d_in[16];
  float* out = (float*)d_out;

  char* ws = (char*)d_ws;
  size_t off = 0;
  float* h_cur = (float*)(ws + off); off += (size_t)N_NODES*HID*4;
  float* dist  = (float*)(ws + off); off += (size_t)N_EDGES*4;
  u16*   aggb  = (u16*)  (ws + off); off += (size_t)N_NODES*NF*2;
  u16*   hxb   = (u16*)  (ws + off); off += (size_t)N_NODES*NF*2;
  u16*   tab   = (u16*)  (ws + off); off += (size_t)NL*TAB2*NF*2;
  u16*   w1T   = (u16*)  (ws + off); off += (size_t)NL*HID*NF*2;
  u16*   w2T   = (u16*)  (ws + off); off += (size_t)NL*NF*HID*2;
  u16*   lT    = (u16*)  (ws + off); off += (size_t)NL*HID*HID*2;
  unsigned* csr_pack = (unsigned*)(ws + off); off += (size_t)N_EDGES*4;
  int* deg       = (int*)(ws + off); off += (size_t)N_NODES*4;
  int* row_start = (int*)(ws + off); off += (size_t)(N_NODES + 64)*4;
  int* cursor    = (int*)(ws + off); off += (size_t)N_NODES*4;

  hipMemsetAsync(out, 0, NSEG*sizeof(float), stream);
  hipMemsetAsync(deg, 0, N_NODES*sizeof(int), stream);
  hipMemsetAsync(cursor, 0, N_NODES*sizeof(int), stream);
  hipMemcpyAsync(h_cur, h, (size_t)N_NODES*HID*sizeof(float), hipMemcpyDeviceToDevice, stream);

  k_dist<<<2048, 256, 0, stream>>>(ei, pos, dist, deg);
  k_scan<<<1, 1024, 0, stream>>>(deg, row_start);
  k_scatter<<<2048, 256, 0, stream>>>(ei, dist, row_start, cursor, csr_pack);
  k_table<<<NL*TAB2, 128, 0, stream>>>(mlp_w1, mlp_b1, mlp_w2, mlp_b2, tab);
  k_wconv<<<NL*128, 128, 0, stream>>>(cl1w, w1T);
  k_wconv<<<NL*128, 128, 0, stream>>>(cl2w, w2T);
  k_wconv<<<NL*128, 128, 0, stream>>>(linw, lT);

  const int NBLK = (N_NODES + 63) / 64; // 782
  k_lin1m<<<NBLK, 256, 0, stream>>>(h_cur, w1T, hxb);
  for (int l = 0; l < NL; l++){
    k_edgeagg<<<N_NODES/4, 256, 0, stream>>>(row_start, csr_pack,
                                             tab + (size_t)l*TAB2*NF, hxb, aggb);
    const u16* w1n = (l + 1 < NL) ? (w1T + (size_t)(l+1)*HID*NF) : nullptr;
    k_nodefuse<<<NBLK, 256, 0, stream>>>(aggb, w2T + (size_t)l*NF*HID, cl2b + (size_t)l*HID,
                                         lT + (size_t)l*HID*HID, linb + (size_t)l*HID,
                                         h_cur, w1n, hxb);
  }
  k_out<<<256, 256, 0, stream>>>(h_cur, o1w, o1b, o2w, o2b, batch, out);
}

// Round 6
// 1039.029 us; speedup vs baseline: 3.7586x; 1.0957x over previous
//
#include <hip/hip_runtime.h>
#include <math.h>

#define N_NODES 50000
#define N_EDGES 1600000
#define HID 128
#define NF 128
#define NG 50
#define NL 6
#define NSEG 64
#define TAB2 4096
#define CUTOFF 20.0f
#define LOG2F_ 0.6931471805599453f

typedef unsigned short u16;
typedef __attribute__((ext_vector_type(8))) short short8;            // 8 bf16 MFMA A/B frag
typedef __attribute__((ext_vector_type(8))) unsigned short ushort8;  // 16B bf16 load
typedef __attribute__((ext_vector_type(4))) float f32x4;             // MFMA C/D frag

__device__ __forceinline__ float ssp(float x){
  float sp = fmaxf(x, 0.f) + log1pf(expf(-fabsf(x)));
  return sp - LOG2F_;
}
__device__ __forceinline__ float b2f(u16 u){
  unsigned v = ((unsigned)u) << 16; float f; __builtin_memcpy(&f, &v, 4); return f;
}
__device__ __forceinline__ u16 f2b(float f){
  unsigned u; __builtin_memcpy(&u, &f, 4);
  u += 0x7FFFu + ((u >> 16) & 1u);
  return (u16)(u >> 16);
}
// XOR-swizzled byte offset within a [16][128] bf16 tile (256B rows).
__device__ __forceinline__ int swz(int row, int colb){
  return row*256 + (colb ^ ((row & 15) << 4));
}

// ---------------- edge distance + degree histogram (fused) ----------------
__global__ __launch_bounds__(256) void k_dist(const int* __restrict__ ei,
                                              const float* __restrict__ pos,
                                              float* __restrict__ dist,
                                              int* __restrict__ deg){
  for (int e = blockIdx.x*blockDim.x + threadIdx.x; e < N_EDGES; e += gridDim.x*blockDim.x){
    int s = ei[e], t = ei[N_EDGES + e];
    float dx = pos[3*s]   - pos[3*t];
    float dy = pos[3*s+1] - pos[3*t+1];
    float dz = pos[3*s+2] - pos[3*t+2];
    dist[e] = sqrtf(dx*dx + dy*dy + dz*dz);
    atomicAdd(&deg[t], 1);
  }
}

__global__ __launch_bounds__(1024) void k_scan(const int* __restrict__ deg, int* __restrict__ row_start){
  __shared__ int sums[1024];
  const int t = threadIdx.x;
  const int CH = (N_NODES + 1023) / 1024; // 49
  const int base = t * CH;
  int s = 0;
  for (int i = 0; i < CH; i++){ int idx = base + i; if (idx < N_NODES) s += deg[idx]; }
  sums[t] = s; __syncthreads();
  for (int off = 1; off < 1024; off <<= 1){
    int v = (t >= off) ? sums[t - off] : 0;
    __syncthreads();
    sums[t] += v;
    __syncthreads();
  }
  int run = (t == 0) ? 0 : sums[t - 1];
  for (int i = 0; i < CH; i++){
    int idx = base + i;
    if (idx < N_NODES){ row_start[idx] = run; run += deg[idx]; }
  }
  if (t == 1023) row_start[N_NODES] = run;
}

// pack (table_index<<16 | src) per CSR slot
__global__ __launch_bounds__(256) void k_scatter(const int* __restrict__ ei,
                                                 const float* __restrict__ dist,
                                                 const int* __restrict__ row_start,
                                                 int* __restrict__ cursor,
                                                 unsigned* __restrict__ csr_pack){
  const float INV_STEP = (TAB2 - 1) / CUTOFF;
  for (int e = blockIdx.x*blockDim.x + threadIdx.x; e < N_EDGES; e += gridDim.x*blockDim.x){
    int dn = ei[N_EDGES + e];
    int slot = atomicAdd(&cursor[dn], 1);
    int p = row_start[dn] + slot;
    int j = (int)(dist[e] * INV_STEP + 0.5f);
    if (j > TAB2 - 1) j = TAB2 - 1;
    csr_pack[p] = ((unsigned)j << 16) | (unsigned)ei[e];
  }
}

// ---------------- filter table: W_l(d)*C(d), bf16, plain [l][j][f] ----------------
__global__ __launch_bounds__(128) void k_table(const float* __restrict__ w1, const float* __restrict__ b1,
                                               const float* __restrict__ w2, const float* __restrict__ b2,
                                               u16* __restrict__ tab){
  int l = blockIdx.x / TAB2, j = blockIdx.x % TAB2;
  int tid = threadIdx.x;
  float d = j * (CUTOFF / (TAB2 - 1));
  __shared__ float ea[NG];
  __shared__ float sbuf[NF];
  if (tid < NG){
    const float gstep = CUTOFF / (NG - 1);
    const float coeff = -0.5f / (gstep * gstep);
    float u = d - tid * gstep;
    ea[tid] = expf(coeff * u * u);
  }
  __syncthreads();
  float z = b1[l*NF + tid];
  for (int k = 0; k < NG; k++) z += ea[k] * w1[(l*NG + k)*NF + tid];
  sbuf[tid] = ssp(z);
  __syncthreads();
  float W = b2[l*NF + tid];
  for (int k = 0; k < NF; k++) W += sbuf[k] * w2[(l*NF + k)*NF + tid];
  float C = 0.5f * (cosf(d * (float)M_PI / CUTOFF) + 1.f);
  tab[((size_t)l*TAB2 + j)*NF + tid] = f2b(W * C);
}

// ---------------- weight convert: [in][out] fp32 -> [out][in] bf16 (128x128) ----------------
__global__ __launch_bounds__(128) void k_wconv(const float* __restrict__ w, u16* __restrict__ wT){
  int m = blockIdx.x >> 7, o = blockIdx.x & 127;
  int i = threadIdx.x;
  wT[((size_t)m*128 + o)*128 + i] = f2b(w[((size_t)m*128 + i)*128 + o]);
}
// [128][64] fp32 -> [64][128] bf16
__global__ __launch_bounds__(128) void k_wconv64(const float* __restrict__ w, u16* __restrict__ wT){
  int o = blockIdx.x;
  int i = threadIdx.x;
  wT[o*128 + i] = f2b(w[i*64 + o]);
}

// ---------------- layer-0 lin1: hxb = bf16(h @ w1) via MFMA ----------------
__global__ __launch_bounds__(256) void k_lin1m(const float* __restrict__ h,
                                               const u16* __restrict__ w1T,
                                               u16* __restrict__ hxb){
  int tid = threadIdx.x;
  int wv = tid >> 6, l = tid & 63;
  int n0 = blockIdx.x * 64 + wv * 16;
  if (n0 >= N_NODES) return;
  int li = l & 15, lh = l >> 4;
  __shared__ u16 tiles[4][16*128];
  char* tb = (char*)&tiles[wv][0];

  short8 a[4];
  #pragma unroll
  for (int kc = 0; kc < 4; kc++){
    const float* p = &h[(size_t)(n0 + li)*HID + kc*32 + lh*8];
    union { short8 v; u16 u[8]; } t;
    #pragma unroll
    for (int e = 0; e < 8; e++) t.u[e] = f2b(p[e]);
    a[kc] = t.v;
  }
  #pragma unroll
  for (int fc = 0; fc < 8; fc++){
    f32x4 acc = {0.f,0.f,0.f,0.f};
    #pragma unroll
    for (int kc = 0; kc < 4; kc++){
      short8 b = *(const short8*)&w1T[(size_t)(fc*16 + li)*HID + kc*32 + lh*8];
      acc = __builtin_amdgcn_mfma_f32_16x16x32_bf16(a[kc], b, acc, 0, 0, 0);
    }
    #pragma unroll
    for (int r = 0; r < 4; r++)
      *(u16*)(tb + swz(lh*4 + r, fc*32 + li*2)) = f2b(acc[r]);
  }
  #pragma unroll
  for (int g = 0; g < 4; g++){
    int row = g*4 + lh;
    short8 v = *(const short8*)(tb + swz(row, li*16));
    *(short8*)&hxb[(size_t)(n0 + row)*NF + li*8] = v;
  }
}

// ---------------- edge aggregation: 8 edges/wave-iter (2 per 16-lane group), dual acc ----------------
__global__ __launch_bounds__(256) void k_edgeagg(const int* __restrict__ row_start,
                                                 const unsigned* __restrict__ csr_pack,
                                                 const u16* __restrict__ tab_l,
                                                 const u16* __restrict__ hxb,
                                                 u16* __restrict__ aggb){
  int wave = threadIdx.x >> 6, lane = threadIdx.x & 63;
  int i = blockIdx.x * 4 + wave;
  int li = lane & 15, g = lane >> 4;
  int rs = row_start[i], re = row_start[i + 1];
  float acc0[8], acc1[8];
  #pragma unroll
  for (int r = 0; r < 8; r++){ acc0[r] = 0.f; acc1[r] = 0.f; }
  for (int p = rs + g; p < re; p += 8){
    int p1 = p + 4;
    bool ok1 = p1 < re;
    unsigned v0 = csr_pack[p];
    unsigned v1 = ok1 ? csr_pack[p1] : 0u;
    int s0 = (int)(v0 & 0xFFFFu), j0 = (int)(v0 >> 16);
    ushort8 hv0 = *(const ushort8*)&hxb[(size_t)s0 * NF + li*8];
    ushort8 wv0 = *(const ushort8*)&tab_l[(size_t)j0 * NF + li*8];
    if (ok1){
      int s1 = (int)(v1 & 0xFFFFu), j1 = (int)(v1 >> 16);
      ushort8 hv1 = *(const ushort8*)&hxb[(size_t)s1 * NF + li*8];
      ushort8 wv1 = *(const ushort8*)&tab_l[(size_t)j1 * NF + li*8];
      #pragma unroll
      for (int r = 0; r < 8; r++)
        acc1[r] += b2f(hv1[r]) * b2f(wv1[r]);
    }
    #pragma unroll
    for (int r = 0; r < 8; r++)
      acc0[r] += b2f(hv0[r]) * b2f(wv0[r]);
  }
  #pragma unroll
  for (int r = 0; r < 8; r++){
    float a = acc0[r] + acc1[r];
    a += __shfl_xor(a, 16);
    a += __shfl_xor(a, 32);
    acc0[r] = a;
  }
  if (g == 0){
    union { short8 v; u16 u[8]; } o;
    #pragma unroll
    for (int r = 0; r < 8; r++) o.u[r] = f2b(acc0[r]);
    *(short8*)&aggb[(size_t)i * NF + li*8] = o.v;
  }
}

// ---------------- fused node update via MFMA ----------------
__global__ __launch_bounds__(256) void k_nodefuse(const u16* __restrict__ aggb,
                                                  const u16* __restrict__ w2T, const float* __restrict__ b2b,
                                                  const u16* __restrict__ lT,  const float* __restrict__ linb,
                                                  float* __restrict__ h,
                                                  const u16* __restrict__ w1nT,
                                                  u16* __restrict__ hxb){
  int tid = threadIdx.x;
  int wv = tid >> 6, l = tid & 63;
  int n0 = blockIdx.x * 64 + wv * 16;
  if (n0 >= N_NODES) return;
  int li = l & 15, lh = l >> 4;
  __shared__ u16 tiles[4][16*128];
  char* tb = (char*)&tiles[wv][0];

  short8 a[4];
  #pragma unroll
  for (int kc = 0; kc < 4; kc++)
    a[kc] = *(const short8*)&aggb[(size_t)(n0 + li)*NF + kc*32 + lh*8];

  #pragma unroll
  for (int fc = 0; fc < 8; fc++){
    f32x4 acc = {0.f,0.f,0.f,0.f};
    #pragma unroll
    for (int kc = 0; kc < 4; kc++){
      short8 b = *(const short8*)&w2T[(size_t)(fc*16 + li)*NF + kc*32 + lh*8];
      acc = __builtin_amdgcn_mfma_f32_16x16x32_bf16(a[kc], b, acc, 0, 0, 0);
    }
    float bias = b2b[fc*16 + li];
    #pragma unroll
    for (int r = 0; r < 4; r++){
      float s = ssp(acc[r] + bias);
      *(u16*)(tb + swz(lh*4 + r, fc*32 + li*2)) = f2b(s);
    }
  }

  short8 a2[4];
  #pragma unroll
  for (int kc = 0; kc < 4; kc++)
    a2[kc] = *(const short8*)(tb + swz(li, kc*64 + lh*16));

  #pragma unroll
  for (int fc = 0; fc < 8; fc++){
    f32x4 acc = {0.f,0.f,0.f,0.f};
    #pragma unroll
    for (int kc = 0; kc < 4; kc++){
      short8 b = *(const short8*)&lT[(size_t)(fc*16 + li)*HID + kc*32 + lh*8];
      acc = __builtin_amdgcn_mfma_f32_16x16x32_bf16(a2[kc], b, acc, 0, 0, 0);
    }
    float bias = linb[fc*16 + li];
    #pragma unroll
    for (int r = 0; r < 4; r++){
      int i = lh*4 + r;
      size_t off = (size_t)(n0 + i)*HID + fc*16 + li;
      float hn = h[off] + acc[r] + bias;
      h[off] = hn;
      if (w1nT) *(u16*)(tb + swz(i, fc*32 + li*2)) = f2b(hn);
    }
  }
  if (!w1nT) return;

  short8 a3[4];
  #pragma unroll
  for (int kc = 0; kc < 4; kc++)
    a3[kc] = *(const short8*)(tb + swz(li, kc*64 + lh*16));
  #pragma unroll
  for (int fc = 0; fc < 8; fc++){
    f32x4 acc = {0.f,0.f,0.f,0.f};
    #pragma unroll
    for (int kc = 0; kc < 4; kc++){
      short8 b = *(const short8*)&w1nT[(size_t)(fc*16 + li)*HID + kc*32 + lh*8];
      acc = __builtin_amdgcn_mfma_f32_16x16x32_bf16(a3[kc], b, acc, 0, 0, 0);
    }
    #pragma unroll
    for (int r = 0; r < 4; r++)
      *(u16*)(tb + swz(lh*4 + r, fc*32 + li*2)) = f2b(acc[r]);
  }
  #pragma unroll
  for (int g = 0; g < 4; g++){
    int row = g*4 + lh;
    short8 v = *(const short8*)(tb + swz(row, li*16));
    *(short8*)&hxb[(size_t)(n0 + row)*NF + li*8] = v;
  }
}

// ---------------- readout via MFMA + wave segmented scan ----------------
// per 16-node wave tile: o[n] = ssp(h@o1w + o1b)@o2w + o2b ; segment-sum into out
__global__ __launch_bounds__(256) void k_out(const float* __restrict__ h,
                                             const u16* __restrict__ o1wT, const float* __restrict__ b1,
                                             const float* __restrict__ w2, const float* __restrict__ b2,
                                             const int* __restrict__ batch, float* __restrict__ out){
  int tid = threadIdx.x;
  int wv = tid >> 6, l = tid & 63;
  int base = blockIdx.x * 64 + wv * 16;
  if (base >= N_NODES) return;
  int li = l & 15, lh = l >> 4;
  __shared__ float o_s[4][16];

  // A frags: 16 h rows -> bf16
  short8 a[4];
  #pragma unroll
  for (int kc = 0; kc < 4; kc++){
    const float* p = &h[(size_t)(base + li)*HID + kc*32 + lh*8];
    union { short8 v; u16 u[8]; } t;
    #pragma unroll
    for (int e = 0; e < 8; e++) t.u[e] = f2b(p[e]);
    a[kc] = t.v;
  }
  float psum[4] = {0.f,0.f,0.f,0.f};
  #pragma unroll
  for (int fc = 0; fc < 4; fc++){
    f32x4 acc = {0.f,0.f,0.f,0.f};
    #pragma unroll
    for (int kc = 0; kc < 4; kc++){
      short8 b = *(const short8*)&o1wT[(size_t)(fc*16 + li)*HID + kc*32 + lh*8];
      acc = __builtin_amdgcn_mfma_f32_16x16x32_bf16(a[kc], b, acc, 0, 0, 0);
    }
    int col = fc*16 + li;
    float bias = b1[col], w2v = w2[col];
    #pragma unroll
    for (int r = 0; r < 4; r++)
      psum[r] += ssp(acc[r] + bias) * w2v;
  }
  // reduce over the 16 cols held across li
  #pragma unroll
  for (int r = 0; r < 4; r++){
    psum[r] += __shfl_xor(psum[r], 1);
    psum[r] += __shfl_xor(psum[r], 2);
    psum[r] += __shfl_xor(psum[r], 4);
    psum[r] += __shfl_xor(psum[r], 8);
  }
  float b2v = b2[0];
  if (li == 0){
    #pragma unroll
    for (int r = 0; r < 4; r++) o_s[wv][lh*4 + r] = psum[r] + b2v;
  }
  // wave-local segmented scan over the 16 nodes (batch sorted)
  float v = o_s[wv][li];
  int n2 = base + li;
  int seg = batch[n2];
  int segn = (li < 15) ? batch[n2 + 1] : -1;
  #pragma unroll
  for (int off = 1; off <= 8; off <<= 1){
    float vv = __shfl_up(v, off);
    int   ss = __shfl_up(seg, off);
    if (li >= off && ss == seg) v += vv;
  }
  if (l < 16 && (li == 15 || segn != seg)) atomicAdd(&out[seg], v);
}

extern "C" void kernel_launch(void* const* d_in, const int* in_sizes, int n_in,
                              void* d_out, int out_size, void* d_ws, size_t ws_size,
                              hipStream_t stream) {
  const float* h     = (const float*)d_in[0];
  const float* pos   = (const float*)d_in[1];
  const int*   ei    = (const int*)d_in[2];
  const int*   batch = (const int*)d_in[3];
  const float* mlp_w1 = (const float*)d_in[4];
  const float* mlp_b1 = (const float*)d_in[5];
  const float* mlp_w2 = (const float*)d_in[6];
  const float* mlp_b2 = (const float*)d_in[7];
  const float* cl1w  = (const float*)d_in[8];
  const float* cl2w  = (const float*)d_in[9];
  const float* cl2b  = (const float*)d_in[10];
  const float* linw  = (const float*)d_in[11];
  const float* linb  = (const float*)d_in[12];
  const float* o1w   = (const float*)d_in[13];
  const float* o1b   = (const float*)d_in[14];
  const float* o2w   = (const float*)d_in[15];
  const float* o2b   = (const float*)d_in[16];
  float* out = (float*)d_out;

  char* ws = (char*)d_ws;
  size_t off = 0;
  float* h_cur = (float*)(ws + off); off += (size_t)N_NODES*HID*4;
  float* dist  = (float*)(ws + off); off += (size_t)N_EDGES*4;
  u16*   aggb  = (u16*)  (ws + off); off += (size_t)N_NODES*NF*2;
  u16*   hxb   = (u16*)  (ws + off); off += (size_t)N_NODES*NF*2;
  u16*   tab   = (u16*)  (ws + off); off += (size_t)NL*TAB2*NF*2;
  u16*   w1T   = (u16*)  (ws + off); off += (size_t)NL*HID*NF*2;
  u16*   w2T   = (u16*)  (ws + off); off += (size_t)NL*NF*HID*2;
  u16*   lT    = (u16*)  (ws + off); off += (size_t)NL*HID*HID*2;
  u16*   o1wT  = (u16*)  (ws + off); off += (size_t)64*HID*2;
  unsigned* csr_pack = (unsigned*)(ws + off); off += (size_t)N_EDGES*4;
  int* deg       = (int*)(ws + off); off += (size_t)N_NODES*4;
  int* row_start = (int*)(ws + off); off += (size_t)(N_NODES + 64)*4;
  int* cursor    = (int*)(ws + off); off += (size_t)N_NODES*4;

  hipMemsetAsync(out, 0, NSEG*sizeof(float), stream);
  hipMemsetAsync(deg, 0, N_NODES*sizeof(int), stream);
  hipMemsetAsync(cursor, 0, N_NODES*sizeof(int), stream);
  hipMemcpyAsync(h_cur, h, (size_t)N_NODES*HID*sizeof(float), hipMemcpyDeviceToDevice, stream);

  k_dist<<<2048, 256, 0, stream>>>(ei, pos, dist, deg);
  k_scan<<<1, 1024, 0, stream>>>(deg, row_start);
  k_scatter<<<2048, 256, 0, stream>>>(ei, dist, row_start, cursor, csr_pack);
  k_table<<<NL*TAB2, 128, 0, stream>>>(mlp_w1, mlp_b1, mlp_w2, mlp_b2, tab);
  k_wconv<<<NL*128, 128, 0, stream>>>(cl1w, w1T);
  k_wconv<<<NL*128, 128, 0, stream>>>(cl2w, w2T);
  k_wconv<<<NL*128, 128, 0, stream>>>(linw, lT);
  k_wconv64<<<64, 128, 0, stream>>>(o1w, o1wT);

  const int NBLK = (N_NODES + 63) / 64; // 782
  k_lin1m<<<NBLK, 256, 0, stream>>>(h_cur, w1T, hxb);
  for (int l = 0; l < NL; l++){
    k_edgeagg<<<N_NODES/4, 256, 0, stream>>>(row_start, csr_pack,
                                             tab + (size_t)l*TAB2*NF, hxb, aggb);
    const u16* w1n = (l + 1 < NL) ? (w1T + (size_t)(l+1)*HID*NF) : nullptr;
    k_nodefuse<<<NBLK, 256, 0, stream>>>(aggb, w2T + (size_t)l*NF*HID, cl2b + (size_t)l*HID,
                                         lT + (size_t)l*HID*HID, linb + (size_t)l*HID,
                                         h_cur, w1n, hxb);
  }
  k_out<<<NBLK, 256, 0, stream>>>(h_cur, o1wT, o1b, o2w, o2b, batch, out);
}